// Round 9
// baseline (305.295 us; speedup 1.0000x reference)
//
#include <hip/hip_runtime.h>

#define B_ 16
#define L_ 512
#define H_ 256
#define V_ 32000
#define HALF_ 128

typedef __attribute__((ext_vector_type(8))) short short8;
typedef __attribute__((ext_vector_type(4))) float floatx4;

__device__ __forceinline__ unsigned short f2bf(float x) {
  unsigned int u = __float_as_uint(x);
  unsigned int r = (u + 0x7FFFu + ((u >> 16) & 1u)) >> 16;
  return (unsigned short)r;
}

template <int CTRL>
__device__ __forceinline__ float dpp_xor_add(float x) {
  int y = __builtin_amdgcn_mov_dpp(__float_as_int(x), CTRL, 0xf, 0xf, true);
  return x + __int_as_float(y);
}

// butterfly sum over aligned 16-lane groups; ALL lanes get the result
__device__ __forceinline__ float redu16(float p) {
  p = dpp_xor_add<0xB1>(p);   // xor1
  p = dpp_xor_add<0x4E>(p);   // xor2
  p = dpp_xor_add<0x141>(p);  // row_half_mirror
  p = dpp_xor_add<0x140>(p);  // row_mirror
  return p;
}

// async global->LDS copy, 16B per lane, wave-uniform LDS base
__device__ __forceinline__ void async_cp16(const float* g, float* l) {
  __builtin_amdgcn_global_load_lds(
      (const __attribute__((address_space(1))) void*)g,
      (__attribute__((address_space(3))) void*)l, 16, 0, 0);
}

// load 8 fp32, convert to 8 bf16 packed in uint4
__device__ __forceinline__ uint4 load8cvt(const float* p) {
  float4 a = ((const float4*)p)[0];
  float4 b = ((const float4*)p)[1];
  uint4 r;
  r.x = (unsigned)f2bf(a.x) | ((unsigned)f2bf(a.y) << 16);
  r.y = (unsigned)f2bf(a.z) | ((unsigned)f2bf(a.w) << 16);
  r.z = (unsigned)f2bf(b.x) | ((unsigned)f2bf(b.y) << 16);
  r.w = (unsigned)f2bf(b.z) | ((unsigned)f2bf(b.w) << 16);
  return r;
}

// ---------------- prep: weight fp32->bf16 conversion ----------------
__global__ __launch_bounds__(256) void prep_kernel(const float* __restrict__ W1,
                                                   const float* __restrict__ W2,
                                                   const float* __restrict__ Ws,
                                                   const float* __restrict__ We,
                                                   unsigned short* __restrict__ W1b,
                                                   unsigned short* __restrict__ W2b,
                                                   unsigned short* __restrict__ Wcb) {
  int i = blockIdx.x * 256 + threadIdx.x;  // 0..327679
  if (i < 131072) W1b[i] = f2bf(W1[i]);
  else if (i < 262144) W2b[i - 131072] = f2bf(W2[i - 131072]);
  else if (i < 294912) Wcb[i - 262144] = f2bf(Ws[i - 262144]);
  else Wcb[i - 262144] = f2bf(We[i - 294912]);
}

// ---------------- GEMM1: a1 = relu(embed[seq] @ W1^T + b1) -> bf16 (gather fused) ----------------
__global__ __launch_bounds__(256) void gemm1_kernel(const int* __restrict__ seq,
                                                    const float* __restrict__ embed,
                                                    const unsigned short* __restrict__ W1b,
                                                    const float* __restrict__ b1,
                                                    unsigned short* __restrict__ a1b) {
  __shared__ unsigned short As[128 * 40];
  __shared__ unsigned short Bs[128 * 40];
  int tid = threadIdx.x;
  int wave = tid >> 6, lane = tid & 63;
  int wm = (wave >> 1) * 64, wn = (wave & 1) * 64;
  int quad = lane >> 4, l15 = lane & 15;
  int bm = blockIdx.y * 128, bn = blockIdx.x * 128;
  int sr = tid >> 2, sq = tid & 3;

  int tok0 = seq[bm + sr];
  int tok1 = seq[bm + 64 + sr];

  floatx4 zero = {0.f, 0.f, 0.f, 0.f};
  floatx4 acc[4][4];
#pragma unroll
  for (int fi = 0; fi < 4; fi++)
#pragma unroll
    for (int fj = 0; fj < 4; fj++) acc[fi][fj] = zero;

  uint4 av0 = load8cvt(embed + (size_t)tok0 * H_ + sq * 8);
  uint4 av1 = load8cvt(embed + (size_t)tok1 * H_ + sq * 8);
  uint4 bv0 = *(const uint4*)(W1b + (size_t)(bn + sr) * 256 + sq * 8);
  uint4 bv1 = *(const uint4*)(W1b + (size_t)(bn + 64 + sr) * 256 + sq * 8);

  for (int k0 = 0; k0 < 256; k0 += 32) {
    __syncthreads();
    *(uint4*)(As + sr * 40 + sq * 8) = av0;
    *(uint4*)(As + (64 + sr) * 40 + sq * 8) = av1;
    *(uint4*)(Bs + sr * 40 + sq * 8) = bv0;
    *(uint4*)(Bs + (64 + sr) * 40 + sq * 8) = bv1;
    __syncthreads();
    if (k0 + 32 < 256) {
      av0 = load8cvt(embed + (size_t)tok0 * H_ + k0 + 32 + sq * 8);
      av1 = load8cvt(embed + (size_t)tok1 * H_ + k0 + 32 + sq * 8);
      bv0 = *(const uint4*)(W1b + (size_t)(bn + sr) * 256 + k0 + 32 + sq * 8);
      bv1 = *(const uint4*)(W1b + (size_t)(bn + 64 + sr) * 256 + k0 + 32 + sq * 8);
    }
    short8 af[4], bf[4];
#pragma unroll
    for (int f = 0; f < 4; f++) {
      af[f] = *(const short8*)(As + (wm + f * 16 + l15) * 40 + quad * 8);
      bf[f] = *(const short8*)(Bs + (wn + f * 16 + l15) * 40 + quad * 8);
    }
#pragma unroll
    for (int fi = 0; fi < 4; fi++)
#pragma unroll
      for (int fj = 0; fj < 4; fj++)
        acc[fi][fj] = __builtin_amdgcn_mfma_f32_16x16x32_bf16(af[fi], bf[fj], acc[fi][fj], 0, 0, 0);
  }

#pragma unroll
  for (int fi = 0; fi < 4; fi++) {
#pragma unroll
    for (int fj = 0; fj < 4; fj++) {
      int col = bn + wn + fj * 16 + l15;
      float bb = b1[col];
#pragma unroll
      for (int rg = 0; rg < 4; rg++) {
        int row = bm + wm + fi * 16 + quad * 4 + rg;
        float v = fmaxf(acc[fi][fj][rg] + bb, 0.f);
        a1b[(size_t)row * 512 + col] = f2bf(v);
      }
    }
  }
}

// ---------------- MLPK: hn = LN(a1 @ W2^T + b2 + embed[seq]) [LDS] ; then k-proj -> khat/kT ----------------
__global__ __launch_bounds__(256) void mlpk_kernel(const unsigned short* __restrict__ a1b,
                                                   const unsigned short* __restrict__ W2b,
                                                   const float* __restrict__ b2,
                                                   const int* __restrict__ seq,
                                                   const float* __restrict__ embed,
                                                   const float* __restrict__ gamma,
                                                   const float* __restrict__ beta,
                                                   const unsigned short* __restrict__ Wcb,
                                                   float* __restrict__ khat,
                                                   float* __restrict__ kT) {
  __shared__ unsigned short As[32 * 40];
  __shared__ unsigned short Bs[256 * 40];
  __shared__ unsigned short hnS[32 * 264];
  __shared__ float stats[2][2][32];
  int tid = threadIdx.x;
  int wave = tid >> 6, lane = tid & 63;
  int wm = (wave >> 1) * 16, wnh = wave & 1, wn = wnh * 128;
  int quad = lane >> 4, l15 = lane & 15;
  int bm = blockIdx.x * 32;
  int sr = tid >> 2, sq = tid & 3;

  floatx4 zero = {0.f, 0.f, 0.f, 0.f};
  floatx4 acc[8];
#pragma unroll
  for (int fj = 0; fj < 8; fj++) acc[fj] = zero;

  // -------- phase 1: a1 @ W2^T, K=512 --------
  uint4 av, bv[4];
  if (tid < 128) av = *(const uint4*)(a1b + (size_t)(bm + sr) * 512 + sq * 8);
#pragma unroll
  for (int q = 0; q < 4; q++) {
    int unit = q * 256 + tid;
    bv[q] = *(const uint4*)(W2b + (size_t)(unit >> 2) * 512 + (unit & 3) * 8);
  }
  for (int k0 = 0; k0 < 512; k0 += 32) {
    __syncthreads();
    if (tid < 128) *(uint4*)(As + sr * 40 + sq * 8) = av;
#pragma unroll
    for (int q = 0; q < 4; q++) {
      int unit = q * 256 + tid;
      *(uint4*)(Bs + (unit >> 2) * 40 + (unit & 3) * 8) = bv[q];
    }
    __syncthreads();
    if (k0 + 32 < 512) {
      if (tid < 128) av = *(const uint4*)(a1b + (size_t)(bm + sr) * 512 + k0 + 32 + sq * 8);
#pragma unroll
      for (int q = 0; q < 4; q++) {
        int unit = q * 256 + tid;
        bv[q] = *(const uint4*)(W2b + (size_t)(unit >> 2) * 512 + k0 + 32 + (unit & 3) * 8);
      }
    }
    short8 af = *(const short8*)(As + (wm + l15) * 40 + quad * 8);
    short8 bf[8];
#pragma unroll
    for (int fj = 0; fj < 8; fj++)
      bf[fj] = *(const short8*)(Bs + (wn + fj * 16 + l15) * 40 + quad * 8);
#pragma unroll
    for (int fj = 0; fj < 8; fj++)
      acc[fj] = __builtin_amdgcn_mfma_f32_16x16x32_bf16(af, bf[fj], acc[fj], 0, 0, 0);
  }

  // -------- LN epilogue -> hnS (LDS) --------
  int seqv[4];
#pragma unroll
  for (int rg = 0; rg < 4; rg++) seqv[rg] = seq[bm + wm + quad * 4 + rg];
  float v[8][4];
#pragma unroll
  for (int fj = 0; fj < 8; fj++) {
    int col = wn + fj * 16 + l15;
    float bb = b2[col];
#pragma unroll
    for (int rg = 0; rg < 4; rg++)
      v[fj][rg] = acc[fj][rg] + bb + embed[(size_t)seqv[rg] * H_ + col];
  }
  float s_[4], q_[4];
#pragma unroll
  for (int rg = 0; rg < 4; rg++) {
    float s = 0.f, q = 0.f;
#pragma unroll
    for (int fj = 0; fj < 8; fj++) {
      s += v[fj][rg];
      q += v[fj][rg] * v[fj][rg];
    }
    s_[rg] = redu16(s);
    q_[rg] = redu16(q);
  }
  if (l15 == 0) {
#pragma unroll
    for (int rg = 0; rg < 4; rg++) {
      int rlocal = wm + quad * 4 + rg;
      stats[wnh][0][rlocal] = s_[rg];
      stats[wnh][1][rlocal] = q_[rg];
    }
  }
  __syncthreads();
#pragma unroll
  for (int rg = 0; rg < 4; rg++) {
    int rlocal = wm + quad * 4 + rg;
    float sum = stats[0][0][rlocal] + stats[1][0][rlocal];
    float ssq = stats[0][1][rlocal] + stats[1][1][rlocal];
    float mu = sum * (1.f / H_);
    float var = ssq * (1.f / H_) - mu * mu;
    float inv = rsqrtf(var + 1e-5f);
#pragma unroll
    for (int fj = 0; fj < 8; fj++) {
      int col = wn + fj * 16 + l15;
      float y = (v[fj][rg] - mu) * inv * gamma[col] + beta[col];
      hnS[rlocal * 264 + col] = f2bf(y);
    }
  }
  __syncthreads();

  // -------- phase 2: kproj, K=256, A from hnS --------
  floatx4 acc2[8];
#pragma unroll
  for (int fj = 0; fj < 8; fj++) acc2[fj] = zero;
#pragma unroll
  for (int q = 0; q < 4; q++) {
    int unit = q * 256 + tid;
    bv[q] = *(const uint4*)(Wcb + (size_t)(unit >> 2) * 256 + (unit & 3) * 8);
  }
  for (int k0 = 0; k0 < 256; k0 += 32) {
    __syncthreads();
#pragma unroll
    for (int q = 0; q < 4; q++) {
      int unit = q * 256 + tid;
      *(uint4*)(Bs + (unit >> 2) * 40 + (unit & 3) * 8) = bv[q];
    }
    __syncthreads();
    if (k0 + 32 < 256) {
#pragma unroll
      for (int q = 0; q < 4; q++) {
        int unit = q * 256 + tid;
        bv[q] = *(const uint4*)(Wcb + (size_t)(unit >> 2) * 256 + k0 + 32 + (unit & 3) * 8);
      }
    }
    short8 af = *(const short8*)(hnS + (wm + l15) * 264 + k0 + quad * 8);
    short8 bf[8];
#pragma unroll
    for (int fj = 0; fj < 8; fj++)
      bf[fj] = *(const short8*)(Bs + (wn + fj * 16 + l15) * 40 + quad * 8);
#pragma unroll
    for (int fj = 0; fj < 8; fj++)
      acc2[fj] = __builtin_amdgcn_mfma_f32_16x16x32_bf16(af, bf[fj], acc2[fj], 0, 0, 0);
  }

  // -------- norm epilogue: khat (permuted fp32) + kT (raw, transposed) --------
  int b = bm >> 9;
  int idxm = b * 2 + wnh;
  int tloc0 = (bm & 511) + wm + quad * 4;
  float inv[4];
#pragma unroll
  for (int rg = 0; rg < 4; rg++) {
    float ssq = 0.f;
#pragma unroll
    for (int fj = 0; fj < 8; fj++) ssq += acc2[fj][rg] * acc2[fj][rg];
    ssq = redu16(ssq);
    inv[rg] = 1.f / fmaxf(sqrtf(ssq), 1e-12f);
  }
#pragma unroll
  for (int fj = 0; fj < 8; fj++) {
    int ch = fj * 16 + l15;             // logical col 0..127
    int j = ch >> 2, e = ch & 3;
    int pj = (j & 1) ? (16 + (j >> 1)) : (j >> 1);  // even granules first
    int pcol = pj * 4 + e;
#pragma unroll
    for (int rg = 0; rg < 4; rg++)
      khat[((size_t)idxm * L_ + tloc0 + rg) * HALF_ + pcol] = acc2[fj][rg] * inv[rg];
    float4 raw = {acc2[fj][0], acc2[fj][1], acc2[fj][2], acc2[fj][3]};
    *(float4*)(kT + (size_t)idxm * (HALF_ * L_) + (size_t)ch * L_ + tloc0) = raw;
  }
}

// ---------------- scan: WY-chunked (T=16), MFMA Gram + readlane solve ----------------
__global__ __launch_bounds__(256) void scan_kernel(const float* __restrict__ khat,
                                                   const float* __restrict__ kT,
                                                   float* __restrict__ c) {
  __shared__ float sk[2][64 * 128];
  int bid = blockIdx.x;
  int idxm = bid & 31;
  int rg = bid >> 5;
  int b = idxm >> 1, mat = idxm & 1;
  const float* kh = khat + (size_t)idxm * L_ * HALF_;
  const float* kTi = kT + (size_t)idxm * HALF_ * L_;

  int tid = threadIdx.x;
  int wave = tid >> 6, lane = tid & 63;
  int seg = tid & 15, rl = tid >> 4;
  int l15 = lane & 15, quad = lane >> 4;
  int r = rg * 16 + rl;
  int c0 = seg * 8;
  const float* krow = kTi + (size_t)r * L_;

  float m[8];
#pragma unroll
  for (int g = 0; g < 8; g++) m[g] = 0.f;

  // stage buf0
#pragma unroll
  for (int j = 0; j < 8; j++)
    async_cp16(kh + wave * 2048 + j * 256 + lane * 4, &sk[0][wave * 2048 + j * 256] + lane * 4);

  // preload raw keys for chunk 0
  float kr[16], nkr[16];
#pragma unroll
  for (int q = 0; q < 4; q++) *(float4*)&kr[q * 4] = *(const float4*)(krow + q * 4);

  __syncthreads();

  const float* lb = &sk[0][0] + seg * 4;

  // one WY chunk of 16 steps; bt = lane-relative key base, gch = global chunk id
  auto do_chunk = [&](const float* bt, int gch, bool last) {
    // G operands from GLOBAL khat (avoids 16-way LDS row-stride conflicts)
    const float* gsrc = kh + (size_t)(gch * 16 + l15) * HALF_;
    floatx4 g4 = {0.f, 0.f, 0.f, 0.f};
#pragma unroll
    for (int kc = 0; kc < 4; kc++) {
      float4 x0 = *(const float4*)(gsrc + kc * 32 + quad * 8);
      float4 x1 = *(const float4*)(gsrc + kc * 32 + quad * 8 + 4);
      uint4 pkk;
      pkk.x = (unsigned)f2bf(x0.x) | ((unsigned)f2bf(x0.y) << 16);
      pkk.y = (unsigned)f2bf(x0.z) | ((unsigned)f2bf(x0.w) << 16);
      pkk.z = (unsigned)f2bf(x1.x) | ((unsigned)f2bf(x1.y) << 16);
      pkk.w = (unsigned)f2bf(x1.z) | ((unsigned)f2bf(x1.w) << 16);
      short8 kf = *(short8*)&pkk;
      g4 = __builtin_amdgcn_mfma_f32_16x16x32_bf16(kf, kf, g4, 0, 0, 0);
    }
    // prefetch next chunk's raw keys
    if (gch < 31) {
#pragma unroll
      for (int q = 0; q < 4; q++)
        *(float4*)&nkr[q * 4] = *(const float4*)(krow + (gch + 1) * 16 + q * 4);
    }
    // phase A: batch dots vs fixed M
    float pp[16];
#pragma unroll
    for (int i = 0; i < 16; i++) {
      float4 ka = *(const float4*)(bt + i * 128);
      float4 kb = *(const float4*)(bt + i * 128 + 64);
      float t0 = m[0] * ka.x + m[1] * ka.y;
      float t1 = m[2] * ka.z + m[3] * ka.w;
      float t2 = m[4] * kb.x + m[5] * kb.y;
      float t3 = m[6] * kb.z + m[7] * kb.w;
      pp[i] = redu16((t0 + t1) + (t2 + t3));
    }
    // phase C: forward substitution (chain = 1 FMA/step)
    float dd[16];
#pragma unroll
    for (int i = 0; i < 16; i++) dd[i] = kr[i] - pp[i];
#pragma unroll
    for (int j = 0; j < 15; j++) {
#pragma unroll
      for (int i = j + 1; i < 16; i++) {
        int gv = __builtin_amdgcn_readlane(__float_as_int(g4[j & 3]), (j >> 2) * 16 + i);
        dd[i] -= __int_as_float(gv) * dd[j];
      }
    }
    // phase D: rank-16 update (skip the final query key on the last chunk)
#pragma unroll
    for (int i = 0; i < 16; i++) {
      if (last && i == 15) break;
      float4 ka = *(const float4*)(bt + i * 128);
      float4 kb = *(const float4*)(bt + i * 128 + 64);
      m[0] += dd[i] * ka.x; m[1] += dd[i] * ka.y;
      m[2] += dd[i] * ka.z; m[3] += dd[i] * ka.w;
      m[4] += dd[i] * kb.x; m[5] += dd[i] * kb.y;
      m[6] += dd[i] * kb.z; m[7] += dd[i] * kb.w;
    }
#pragma unroll
    for (int q = 0; q < 16; q++) kr[q] = nkr[q];
  };

  for (int buf = 0; buf < 8; buf++) {
    if (buf < 7) {
#pragma unroll
      for (int j = 0; j < 8; j++)
        async_cp16(kh + (size_t)(buf + 1) * 8192 + wave * 2048 + j * 256 + lane * 4,
                   &sk[(buf + 1) & 1][wave * 2048 + j * 256] + lane * 4);
    }
    const float* bb = lb + (buf & 1) * 8192;
    int nsub = (buf == 7) ? 3 : 4;
    for (int sub = 0; sub < nsub; sub++) do_chunk(bb + sub * 16 * 128, buf * 4 + sub, false);
    __syncthreads();
  }
  // chunk 31 (keys 496..511; update only i<=14)
  do_chunk(lb + 8192 + 3 * 16 * 128, 31, true);

  // final read with raw last-token key (t=511)
  float q[8];
#pragma unroll
  for (int j = 0; j < 8; j++) q[j] = kTi[(size_t)(c0 + j) * L_ + 511];
  float t0 = m[0] * q[0] + m[1] * q[1];
  float t1 = m[2] * q[2] + m[3] * q[3];
  float t2 = m[4] * q[4] + m[5] * q[5];
  float t3 = m[6] * q[6] + m[7] * q[7];
  float p = redu16((t0 + t1) + (t2 + t3));
  if (seg == 0) c[(size_t)b * H_ + mat * HALF_ + r] = p;
}

// ---------------- r = c @ W_rp^T + b_rp ----------------
__global__ void rp_kernel(const float* __restrict__ c, const float* __restrict__ Wrp,
                          const float* __restrict__ brp, float* __restrict__ r) {
  int b = blockIdx.x;
  int n = threadIdx.x;  // 256
  __shared__ float cs[H_];
  cs[n] = c[(size_t)b * H_ + n];
  __syncthreads();
  const float4* w4 = (const float4*)(Wrp + (size_t)n * H_);
  const float4* c4 = (const float4*)cs;
  float acc = 0.f;
#pragma unroll 8
  for (int k = 0; k < H_ / 4; k++) {
    float4 w = w4[k], cc = c4[k];
    acc += w.x * cc.x + w.y * cc.y + w.z * cc.z + w.w * cc.w;
  }
  r[(size_t)b * H_ + n] = acc + brp[n];
}

// ---------------- out = r @ W_out^T + b_out, coalesced ----------------
__global__ __launch_bounds__(256) void out_kernel(const float* __restrict__ r,
                                                  const float* __restrict__ Wout,
                                                  const float* __restrict__ bout,
                                                  float* __restrict__ out) {
  __shared__ float rs[16 * 272];
  __shared__ float obuf[16 * 68];
  int tid = threadIdx.x;
#pragma unroll
  for (int q = 0; q < 16; q++) {
    int idx = q * 256 + tid;
    int bb = idx >> 8, cc = idx & 255;
    rs[bb * 272 + cc + 4 * (cc >> 6)] = r[idx];
  }
  __syncthreads();
  int row = tid >> 2, part = tid & 3;
  int v = blockIdx.x * 64 + row;
  const float4* w4 = (const float4*)(Wout + (size_t)v * H_ + part * 64);
  float acc[16];
#pragma unroll
  for (int bb = 0; bb < 16; bb++) acc[bb] = 0.f;
#pragma unroll 4
  for (int j = 0; j < 16; j++) {
    float4 w = w4[j];
#pragma unroll
    for (int bb = 0; bb < 16; bb++) {
      float4 rv = *(const float4*)&rs[bb * 272 + part * 68 + j * 4];
      acc[bb] += w.x * rv.x + w.y * rv.y + w.z * rv.z + w.w * rv.w;
    }
  }
  float bo = bout[v];
#pragma unroll
  for (int bb = 0; bb < 16; bb++) {
    acc[bb] = dpp_xor_add<0xB1>(acc[bb]);
    acc[bb] = dpp_xor_add<0x4E>(acc[bb]);
  }
#pragma unroll
  for (int q = 0; q < 4; q++) {
    int bb = part * 4 + q;
    obuf[bb * 68 + row] = acc[bb] + bo;
  }
  __syncthreads();
#pragma unroll
  for (int q = 0; q < 4; q++) {
    int idx = q * 256 + tid;
    int bb = idx >> 6, vl = idx & 63;
    out[(size_t)bb * V_ + blockIdx.x * 64 + vl] = obuf[bb * 68 + vl];
  }
}

extern "C" void kernel_launch(void* const* d_in, const int* in_sizes, int n_in,
                              void* d_out, int out_size, void* d_ws, size_t ws_size,
                              hipStream_t stream) {
  const int* seq = (const int*)d_in[0];
  const float* embed = (const float*)d_in[1];
  const float* W1 = (const float*)d_in[2];
  const float* b1 = (const float*)d_in[3];
  const float* W2 = (const float*)d_in[4];
  const float* b2 = (const float*)d_in[5];
  const float* gamma = (const float*)d_in[6];
  const float* beta = (const float*)d_in[7];
  const float* Wsem = (const float*)d_in[8];
  const float* Wepi = (const float*)d_in[9];
  const float* Wrp = (const float*)d_in[10];
  const float* brp = (const float*)d_in[11];
  const float* Wout = (const float*)d_in[12];
  const float* bout = (const float*)d_in[13];
  float* out = (float*)d_out;

  // Workspace (float-slot offsets), disjoint:
  //  [0       , 2097152)  a1b bf16 [8192,512]
  //  [2097152 , 4194304)  khat fp32 [32,512,128]
  //  [4194304 , 6291456)  kT   fp32 [32,128,512]
  //  [6291456 , 6356992)  W1b bf16 131072
  //  [6356992 , 6422528)  W2b bf16 131072
  //  [6422528 , 6455296)  Wcb bf16 65536
  //  [6455296 , 6459392)  c [16,256]
  //  [6459392 , 6463488)  r [16,256]
  float* ws = (float*)d_ws;
  unsigned short* a1b = (unsigned short*)ws;
  float* khat = ws + 2097152;
  float* kT = ws + 4194304;
  unsigned short* W1b = (unsigned short*)(ws + 6291456);
  unsigned short* W2b = (unsigned short*)(ws + 6356992);
  unsigned short* Wcb = (unsigned short*)(ws + 6422528);
  float* c = ws + 6455296;
  float* r = ws + 6459392;

  // 1. weights -> bf16
  prep_kernel<<<1280, 256, 0, stream>>>(W1, W2, Wsem, Wepi, W1b, W2b, Wcb);
  // 2. a1 = relu(embed[seq] @ W1^T + b1) -> bf16
  gemm1_kernel<<<dim3(4, 64), 256, 0, stream>>>(seq, embed, W1b, b1, a1b);
  // 3. hn = LN(a1 @ W2^T + b2 + embed[seq]) [LDS] ; kproj + normalize -> khat/kT
  mlpk_kernel<<<256, 256, 0, stream>>>(a1b, W2b, b2, seq, embed, gamma, beta, Wcb, khat, kT);
  // 4. WY-chunked delta-rule scan -> c [16,256]
  scan_kernel<<<256, 256, 0, stream>>>(khat, kT, c);
  // 5. r = c @ Wrp^T + brp
  rp_kernel<<<16, 256, 0, stream>>>(c, Wrp, brp, r);
  // 6. out = r @ Wout^T + bout
  out_kernel<<<500, 256, 0, stream>>>(r, Wout, bout, out);
}

// Round 10
// 231.423 us; speedup vs baseline: 1.3192x; 1.3192x over previous
//
#include <hip/hip_runtime.h>

#define B_ 16
#define L_ 512
#define H_ 256
#define V_ 32000
#define HALF_ 128

typedef __attribute__((ext_vector_type(8))) short short8;
typedef __attribute__((ext_vector_type(4))) float floatx4;
typedef __attribute__((ext_vector_type(2))) float float2v;

__device__ __forceinline__ unsigned short f2bf(float x) {
  unsigned int u = __float_as_uint(x);
  unsigned int r = (u + 0x7FFFu + ((u >> 16) & 1u)) >> 16;
  return (unsigned short)r;
}

template <int CTRL>
__device__ __forceinline__ float dpp_xor_add(float x) {
  int y = __builtin_amdgcn_mov_dpp(__float_as_int(x), CTRL, 0xf, 0xf, true);
  return x + __int_as_float(y);
}

// butterfly sum over aligned 16-lane groups; ALL lanes get the result
__device__ __forceinline__ float redu16(float p) {
  p = dpp_xor_add<0xB1>(p);   // xor1
  p = dpp_xor_add<0x4E>(p);   // xor2
  p = dpp_xor_add<0x141>(p);  // row_half_mirror
  p = dpp_xor_add<0x140>(p);  // row_mirror
  return p;
}

// packed fp32 math (VOP3P) — 2 lanes of fp32 per instruction
__device__ __forceinline__ float2v pk_fma(float2v a, float2v b, float2v c) {
  float2v d;
  asm("v_pk_fma_f32 %0, %1, %2, %3" : "=v"(d) : "v"(a), "v"(b), "v"(c));
  return d;
}
__device__ __forceinline__ float2v pk_mul(float2v a, float2v b) {
  float2v d;
  asm("v_pk_mul_f32 %0, %1, %2" : "=v"(d) : "v"(a), "v"(b));
  return d;
}

// async global->LDS copy, 16B per lane, wave-uniform LDS base
__device__ __forceinline__ void async_cp16(const float* g, float* l) {
  __builtin_amdgcn_global_load_lds(
      (const __attribute__((address_space(1))) void*)g,
      (__attribute__((address_space(3))) void*)l, 16, 0, 0);
}

// load 8 fp32, convert to 8 bf16 packed in uint4
__device__ __forceinline__ uint4 load8cvt(const float* p) {
  float4 a = ((const float4*)p)[0];
  float4 b = ((const float4*)p)[1];
  uint4 r;
  r.x = (unsigned)f2bf(a.x) | ((unsigned)f2bf(a.y) << 16);
  r.y = (unsigned)f2bf(a.z) | ((unsigned)f2bf(a.w) << 16);
  r.z = (unsigned)f2bf(b.x) | ((unsigned)f2bf(b.y) << 16);
  r.w = (unsigned)f2bf(b.z) | ((unsigned)f2bf(b.w) << 16);
  return r;
}

// ---------------- prep: weight fp32->bf16 conversion ----------------
__global__ __launch_bounds__(256) void prep_kernel(const float* __restrict__ W1,
                                                   const float* __restrict__ W2,
                                                   const float* __restrict__ Ws,
                                                   const float* __restrict__ We,
                                                   unsigned short* __restrict__ W1b,
                                                   unsigned short* __restrict__ W2b,
                                                   unsigned short* __restrict__ Wcb) {
  int i = blockIdx.x * 256 + threadIdx.x;  // 0..327679
  if (i < 131072) W1b[i] = f2bf(W1[i]);
  else if (i < 262144) W2b[i - 131072] = f2bf(W2[i - 131072]);
  else if (i < 294912) Wcb[i - 262144] = f2bf(Ws[i - 262144]);
  else Wcb[i - 262144] = f2bf(We[i - 294912]);
}

// ---------------- GEMM1: a1 = relu(embed[seq] @ W1^T + b1) -> bf16 (gather fused) ----------------
__global__ __launch_bounds__(256) void gemm1_kernel(const int* __restrict__ seq,
                                                    const float* __restrict__ embed,
                                                    const unsigned short* __restrict__ W1b,
                                                    const float* __restrict__ b1,
                                                    unsigned short* __restrict__ a1b) {
  __shared__ unsigned short As[128 * 40];
  __shared__ unsigned short Bs[128 * 40];
  int tid = threadIdx.x;
  int wave = tid >> 6, lane = tid & 63;
  int wm = (wave >> 1) * 64, wn = (wave & 1) * 64;
  int quad = lane >> 4, l15 = lane & 15;
  int bm = blockIdx.y * 128, bn = blockIdx.x * 128;
  int sr = tid >> 2, sq = tid & 3;

  int tok0 = seq[bm + sr];
  int tok1 = seq[bm + 64 + sr];

  floatx4 zero = {0.f, 0.f, 0.f, 0.f};
  floatx4 acc[4][4];
#pragma unroll
  for (int fi = 0; fi < 4; fi++)
#pragma unroll
    for (int fj = 0; fj < 4; fj++) acc[fi][fj] = zero;

  uint4 av0 = load8cvt(embed + (size_t)tok0 * H_ + sq * 8);
  uint4 av1 = load8cvt(embed + (size_t)tok1 * H_ + sq * 8);
  uint4 bv0 = *(const uint4*)(W1b + (size_t)(bn + sr) * 256 + sq * 8);
  uint4 bv1 = *(const uint4*)(W1b + (size_t)(bn + 64 + sr) * 256 + sq * 8);

  for (int k0 = 0; k0 < 256; k0 += 32) {
    __syncthreads();
    *(uint4*)(As + sr * 40 + sq * 8) = av0;
    *(uint4*)(As + (64 + sr) * 40 + sq * 8) = av1;
    *(uint4*)(Bs + sr * 40 + sq * 8) = bv0;
    *(uint4*)(Bs + (64 + sr) * 40 + sq * 8) = bv1;
    __syncthreads();
    if (k0 + 32 < 256) {
      av0 = load8cvt(embed + (size_t)tok0 * H_ + k0 + 32 + sq * 8);
      av1 = load8cvt(embed + (size_t)tok1 * H_ + k0 + 32 + sq * 8);
      bv0 = *(const uint4*)(W1b + (size_t)(bn + sr) * 256 + k0 + 32 + sq * 8);
      bv1 = *(const uint4*)(W1b + (size_t)(bn + 64 + sr) * 256 + k0 + 32 + sq * 8);
    }
    short8 af[4], bf[4];
#pragma unroll
    for (int f = 0; f < 4; f++) {
      af[f] = *(const short8*)(As + (wm + f * 16 + l15) * 40 + quad * 8);
      bf[f] = *(const short8*)(Bs + (wn + f * 16 + l15) * 40 + quad * 8);
    }
#pragma unroll
    for (int fi = 0; fi < 4; fi++)
#pragma unroll
      for (int fj = 0; fj < 4; fj++)
        acc[fi][fj] = __builtin_amdgcn_mfma_f32_16x16x32_bf16(af[fi], bf[fj], acc[fi][fj], 0, 0, 0);
  }

#pragma unroll
  for (int fi = 0; fi < 4; fi++) {
#pragma unroll
    for (int fj = 0; fj < 4; fj++) {
      int col = bn + wn + fj * 16 + l15;
      float bb = b1[col];
#pragma unroll
      for (int rg = 0; rg < 4; rg++) {
        int row = bm + wm + fi * 16 + quad * 4 + rg;
        float v = fmaxf(acc[fi][fj][rg] + bb, 0.f);
        a1b[(size_t)row * 512 + col] = f2bf(v);
      }
    }
  }
}

// ---------------- MLPK: hn = LN(a1 @ W2^T + b2 + embed[seq]) [LDS] ; then k-proj -> khat/kT ----------------
__global__ __launch_bounds__(256) void mlpk_kernel(const unsigned short* __restrict__ a1b,
                                                   const unsigned short* __restrict__ W2b,
                                                   const float* __restrict__ b2,
                                                   const int* __restrict__ seq,
                                                   const float* __restrict__ embed,
                                                   const float* __restrict__ gamma,
                                                   const float* __restrict__ beta,
                                                   const unsigned short* __restrict__ Wcb,
                                                   float* __restrict__ khat,
                                                   float* __restrict__ kT) {
  __shared__ unsigned short As[32 * 40];
  __shared__ unsigned short Bs[256 * 40];
  __shared__ unsigned short hnS[32 * 264];
  __shared__ float stats[2][2][32];
  int tid = threadIdx.x;
  int wave = tid >> 6, lane = tid & 63;
  int wm = (wave >> 1) * 16, wnh = wave & 1, wn = wnh * 128;
  int quad = lane >> 4, l15 = lane & 15;
  int bm = blockIdx.x * 32;
  int sr = tid >> 2, sq = tid & 3;

  floatx4 zero = {0.f, 0.f, 0.f, 0.f};
  floatx4 acc[8];
#pragma unroll
  for (int fj = 0; fj < 8; fj++) acc[fj] = zero;

  // -------- phase 1: a1 @ W2^T, K=512 --------
  uint4 av, bv[4];
  if (tid < 128) av = *(const uint4*)(a1b + (size_t)(bm + sr) * 512 + sq * 8);
#pragma unroll
  for (int q = 0; q < 4; q++) {
    int unit = q * 256 + tid;
    bv[q] = *(const uint4*)(W2b + (size_t)(unit >> 2) * 512 + (unit & 3) * 8);
  }
  for (int k0 = 0; k0 < 512; k0 += 32) {
    __syncthreads();
    if (tid < 128) *(uint4*)(As + sr * 40 + sq * 8) = av;
#pragma unroll
    for (int q = 0; q < 4; q++) {
      int unit = q * 256 + tid;
      *(uint4*)(Bs + (unit >> 2) * 40 + (unit & 3) * 8) = bv[q];
    }
    __syncthreads();
    if (k0 + 32 < 512) {
      if (tid < 128) av = *(const uint4*)(a1b + (size_t)(bm + sr) * 512 + k0 + 32 + sq * 8);
#pragma unroll
      for (int q = 0; q < 4; q++) {
        int unit = q * 256 + tid;
        bv[q] = *(const uint4*)(W2b + (size_t)(unit >> 2) * 512 + k0 + 32 + (unit & 3) * 8);
      }
    }
    short8 af = *(const short8*)(As + (wm + l15) * 40 + quad * 8);
    short8 bf[8];
#pragma unroll
    for (int fj = 0; fj < 8; fj++)
      bf[fj] = *(const short8*)(Bs + (wn + fj * 16 + l15) * 40 + quad * 8);
#pragma unroll
    for (int fj = 0; fj < 8; fj++)
      acc[fj] = __builtin_amdgcn_mfma_f32_16x16x32_bf16(af, bf[fj], acc[fj], 0, 0, 0);
  }

  // -------- LN epilogue -> hnS (LDS) --------
  int seqv[4];
#pragma unroll
  for (int rg = 0; rg < 4; rg++) seqv[rg] = seq[bm + wm + quad * 4 + rg];
  float v[8][4];
#pragma unroll
  for (int fj = 0; fj < 8; fj++) {
    int col = wn + fj * 16 + l15;
    float bb = b2[col];
#pragma unroll
    for (int rg = 0; rg < 4; rg++)
      v[fj][rg] = acc[fj][rg] + bb + embed[(size_t)seqv[rg] * H_ + col];
  }
  float s_[4], q_[4];
#pragma unroll
  for (int rg = 0; rg < 4; rg++) {
    float s = 0.f, q = 0.f;
#pragma unroll
    for (int fj = 0; fj < 8; fj++) {
      s += v[fj][rg];
      q += v[fj][rg] * v[fj][rg];
    }
    s_[rg] = redu16(s);
    q_[rg] = redu16(q);
  }
  if (l15 == 0) {
#pragma unroll
    for (int rg = 0; rg < 4; rg++) {
      int rlocal = wm + quad * 4 + rg;
      stats[wnh][0][rlocal] = s_[rg];
      stats[wnh][1][rlocal] = q_[rg];
    }
  }
  __syncthreads();
#pragma unroll
  for (int rg = 0; rg < 4; rg++) {
    int rlocal = wm + quad * 4 + rg;
    float sum = stats[0][0][rlocal] + stats[1][0][rlocal];
    float ssq = stats[0][1][rlocal] + stats[1][1][rlocal];
    float mu = sum * (1.f / H_);
    float var = ssq * (1.f / H_) - mu * mu;
    float inv = rsqrtf(var + 1e-5f);
#pragma unroll
    for (int fj = 0; fj < 8; fj++) {
      int col = wn + fj * 16 + l15;
      float y = (v[fj][rg] - mu) * inv * gamma[col] + beta[col];
      hnS[rlocal * 264 + col] = f2bf(y);
    }
  }
  __syncthreads();

  // -------- phase 2: kproj, K=256, A from hnS --------
  floatx4 acc2[8];
#pragma unroll
  for (int fj = 0; fj < 8; fj++) acc2[fj] = zero;
#pragma unroll
  for (int q = 0; q < 4; q++) {
    int unit = q * 256 + tid;
    bv[q] = *(const uint4*)(Wcb + (size_t)(unit >> 2) * 256 + (unit & 3) * 8);
  }
  for (int k0 = 0; k0 < 256; k0 += 32) {
    __syncthreads();
#pragma unroll
    for (int q = 0; q < 4; q++) {
      int unit = q * 256 + tid;
      *(uint4*)(Bs + (unit >> 2) * 40 + (unit & 3) * 8) = bv[q];
    }
    __syncthreads();
    if (k0 + 32 < 256) {
#pragma unroll
      for (int q = 0; q < 4; q++) {
        int unit = q * 256 + tid;
        bv[q] = *(const uint4*)(Wcb + (size_t)(unit >> 2) * 256 + k0 + 32 + (unit & 3) * 8);
      }
    }
    short8 af = *(const short8*)(hnS + (wm + l15) * 264 + k0 + quad * 8);
    short8 bf[8];
#pragma unroll
    for (int fj = 0; fj < 8; fj++)
      bf[fj] = *(const short8*)(Bs + (wn + fj * 16 + l15) * 40 + quad * 8);
#pragma unroll
    for (int fj = 0; fj < 8; fj++)
      acc2[fj] = __builtin_amdgcn_mfma_f32_16x16x32_bf16(af, bf[fj], acc2[fj], 0, 0, 0);
  }

  // -------- norm epilogue: khat (permuted fp32) + kT (raw, transposed) --------
  int b = bm >> 9;
  int idxm = b * 2 + wnh;
  int tloc0 = (bm & 511) + wm + quad * 4;
  float inv[4];
#pragma unroll
  for (int rg = 0; rg < 4; rg++) {
    float ssq = 0.f;
#pragma unroll
    for (int fj = 0; fj < 8; fj++) ssq += acc2[fj][rg] * acc2[fj][rg];
    ssq = redu16(ssq);
    inv[rg] = 1.f / fmaxf(sqrtf(ssq), 1e-12f);
  }
#pragma unroll
  for (int fj = 0; fj < 8; fj++) {
    int ch = fj * 16 + l15;             // logical col 0..127
    int j = ch >> 2, e = ch & 3;
    int pj = (j & 1) ? (16 + (j >> 1)) : (j >> 1);  // even granules first
    int pcol = pj * 4 + e;
#pragma unroll
    for (int rg = 0; rg < 4; rg++)
      khat[((size_t)idxm * L_ + tloc0 + rg) * HALF_ + pcol] = acc2[fj][rg] * inv[rg];
    float4 raw = {acc2[fj][0], acc2[fj][1], acc2[fj][2], acc2[fj][3]};
    *(float4*)(kT + (size_t)idxm * (HALF_ * L_) + (size_t)ch * L_ + tloc0) = raw;
  }
}

// ---------------- scan: LDS-staged khat, 4-deep ring, packed-fp32 step ----------------
#define STEP(KP, KR)                                                     \
  do {                                                                   \
    float2v t_ = pk_mul(m01, KP[0]);                                     \
    t_ = pk_fma(m23, KP[1], t_);                                         \
    t_ = pk_fma(m45, KP[2], t_);                                         \
    t_ = pk_fma(m67, KP[3], t_);                                         \
    float p_ = t_.x + t_.y;                                              \
    p_ = redu16(p_);                                                     \
    float sv_ = (KR) - p_;                                               \
    float2v s2_ = {sv_, sv_};                                            \
    m01 = pk_fma(s2_, KP[0], m01);                                       \
    m23 = pk_fma(s2_, KP[1], m23);                                       \
    m45 = pk_fma(s2_, KP[2], m45);                                       \
    m67 = pk_fma(s2_, KP[3], m67);                                       \
  } while (0)

#define LOADPK(DST, PTR)                                                 \
  do {                                                                   \
    float4 a_ = *(const float4*)(PTR);                                   \
    float4 b_ = *(const float4*)((PTR) + 64);                            \
    DST[0] = (float2v){a_.x, a_.y};                                      \
    DST[1] = (float2v){a_.z, a_.w};                                      \
    DST[2] = (float2v){b_.x, b_.y};                                      \
    DST[3] = (float2v){b_.z, b_.w};                                      \
  } while (0)

__global__ __launch_bounds__(256) void scan_kernel(const float* __restrict__ khat,
                                                   const float* __restrict__ kT,
                                                   float* __restrict__ c) {
  __shared__ float sk[2][64 * 128];  // 2 x 32 KB double buffer
  int bid = blockIdx.x;
  int idxm = bid & 31;
  int rg = bid >> 5;
  int b = idxm >> 1, mat = idxm & 1;
  const float* kh = khat + (size_t)idxm * L_ * HALF_;
  const float* kTi = kT + (size_t)idxm * HALF_ * L_;

  int tid = threadIdx.x;
  int wave = tid >> 6, lane = tid & 63;
  int seg = tid & 15, rl = tid >> 4;
  int r = rg * 16 + rl;
  int c0 = seg * 8;
  const float* krow = kTi + (size_t)r * L_;

  float2v m01 = {0.f, 0.f}, m23 = {0.f, 0.f}, m45 = {0.f, 0.f}, m67 = {0.f, 0.f};

  // stage chunk 0 into buf 0
#pragma unroll
  for (int j = 0; j < 8; j++)
    async_cp16(kh + wave * 2048 + j * 256 + lane * 4, &sk[0][wave * 2048 + j * 256] + lane * 4);
  __syncthreads();

  float4 krn = *(const float4*)(krow);  // raw keys, steps 0..3
  const float* lb = &sk[0][0] + seg * 4;

  // chunks 0..6 (full 64 steps each)
  for (int ch = 0; ch < 7; ch++) {
#pragma unroll
    for (int j = 0; j < 8; j++)
      async_cp16(kh + (size_t)(ch + 1) * 8192 + wave * 2048 + j * 256 + lane * 4,
                 &sk[(ch + 1) & 1][wave * 2048 + j * 256] + lane * 4);
    const float* base = lb + (ch & 1) * 8192;
    float2v pk[4][4];
#pragma unroll
    for (int u = 0; u < 4; u++) LOADPK(pk[u], base + u * 128);
    for (int g = 0; g < 15; g++) {
      float4 krc = krn;
      krn = *(const float4*)(krow + ch * 64 + g * 4 + 4);
#pragma unroll
      for (int u = 0; u < 4; u++) {
        STEP(pk[u], ((u == 0) ? krc.x : (u == 1) ? krc.y : (u == 2) ? krc.z : krc.w));
        int tn = g * 4 + u + 4;
        LOADPK(pk[u], base + tn * 128);
      }
    }
    {
      float4 krc = krn;
      krn = *(const float4*)(krow + ch * 64 + 64);
      STEP(pk[0], krc.x);
      STEP(pk[1], krc.y);
      STEP(pk[2], krc.z);
      STEP(pk[3], krc.w);
    }
    __syncthreads();
  }

  // chunk 7: steps 448..510 (63 updates)
  {
    const float* base = lb + 8192;  // buf 1
    float2v pk[4][4];
#pragma unroll
    for (int u = 0; u < 4; u++) LOADPK(pk[u], base + u * 128);
    for (int g = 0; g < 15; g++) {
      float4 krc = krn;
      krn = *(const float4*)(krow + 448 + g * 4 + 4);
#pragma unroll
      for (int u = 0; u < 4; u++) {
        STEP(pk[u], ((u == 0) ? krc.x : (u == 1) ? krc.y : (u == 2) ? krc.z : krc.w));
        int tn = g * 4 + u + 4;
        LOADPK(pk[u], base + tn * 128);
      }
    }
    float4 krc = krn;  // raw keys for steps 508..511
    STEP(pk[0], krc.x);  // 508
    STEP(pk[1], krc.y);  // 509
    STEP(pk[2], krc.z);  // 510
  }

  // final read with raw last-token key (t=511), gathered from kT columns
  float q[8];
#pragma unroll
  for (int j = 0; j < 8; j++) q[j] = kTi[(size_t)(c0 + j) * L_ + 511];
  float t0 = m01.x * q[0] + m01.y * q[1];
  float t1 = m23.x * q[2] + m23.y * q[3];
  float t2 = m45.x * q[4] + m45.y * q[5];
  float t3 = m67.x * q[6] + m67.y * q[7];
  float p = redu16((t0 + t1) + (t2 + t3));
  if (seg == 0) c[(size_t)b * H_ + mat * HALF_ + r] = p;
}

// ---------------- r = c @ W_rp^T + b_rp ----------------
__global__ void rp_kernel(const float* __restrict__ c, const float* __restrict__ Wrp,
                          const float* __restrict__ brp, float* __restrict__ r) {
  int b = blockIdx.x;
  int n = threadIdx.x;  // 256
  __shared__ float cs[H_];
  cs[n] = c[(size_t)b * H_ + n];
  __syncthreads();
  const float4* w4 = (const float4*)(Wrp + (size_t)n * H_);
  const float4* c4 = (const float4*)cs;
  float acc = 0.f;
#pragma unroll 8
  for (int k = 0; k < H_ / 4; k++) {
    float4 w = w4[k], cc = c4[k];
    acc += w.x * cc.x + w.y * cc.y + w.z * cc.z + w.w * cc.w;
  }
  r[(size_t)b * H_ + n] = acc + brp[n];
}

// ---------------- out = r @ W_out^T + b_out, coalesced ----------------
__global__ __launch_bounds__(256) void out_kernel(const float* __restrict__ r,
                                                  const float* __restrict__ Wout,
                                                  const float* __restrict__ bout,
                                                  float* __restrict__ out) {
  __shared__ float rs[16 * 272];
  __shared__ float obuf[16 * 68];
  int tid = threadIdx.x;
#pragma unroll
  for (int q = 0; q < 16; q++) {
    int idx = q * 256 + tid;
    int bb = idx >> 8, cc = idx & 255;
    rs[bb * 272 + cc + 4 * (cc >> 6)] = r[idx];
  }
  __syncthreads();
  int row = tid >> 2, part = tid & 3;
  int v = blockIdx.x * 64 + row;
  const float4* w4 = (const float4*)(Wout + (size_t)v * H_ + part * 64);
  float acc[16];
#pragma unroll
  for (int bb = 0; bb < 16; bb++) acc[bb] = 0.f;
#pragma unroll 4
  for (int j = 0; j < 16; j++) {
    float4 w = w4[j];
#pragma unroll
    for (int bb = 0; bb < 16; bb++) {
      float4 rv = *(const float4*)&rs[bb * 272 + part * 68 + j * 4];
      acc[bb] += w.x * rv.x + w.y * rv.y + w.z * rv.z + w.w * rv.w;
    }
  }
  float bo = bout[v];
#pragma unroll
  for (int bb = 0; bb < 16; bb++) {
    acc[bb] = dpp_xor_add<0xB1>(acc[bb]);
    acc[bb] = dpp_xor_add<0x4E>(acc[bb]);
  }
#pragma unroll
  for (int q = 0; q < 4; q++) {
    int bb = part * 4 + q;
    obuf[bb * 68 + row] = acc[bb] + bo;
  }
  __syncthreads();
#pragma unroll
  for (int q = 0; q < 4; q++) {
    int idx = q * 256 + tid;
    int bb = idx >> 6, vl = idx & 63;
    out[(size_t)bb * V_ + blockIdx.x * 64 + vl] = obuf[bb * 68 + vl];
  }
}

extern "C" void kernel_launch(void* const* d_in, const int* in_sizes, int n_in,
                              void* d_out, int out_size, void* d_ws, size_t ws_size,
                              hipStream_t stream) {
  const int* seq = (const int*)d_in[0];
  const float* embed = (const float*)d_in[1];
  const float* W1 = (const float*)d_in[2];
  const float* b1 = (const float*)d_in[3];
  const float* W2 = (const float*)d_in[4];
  const float* b2 = (const float*)d_in[5];
  const float* gamma = (const float*)d_in[6];
  const float* beta = (const float*)d_in[7];
  const float* Wsem = (const float*)d_in[8];
  const float* Wepi = (const float*)d_in[9];
  const float* Wrp = (const float*)d_in[10];
  const float* brp = (const float*)d_in[11];
  const float* Wout = (const float*)d_in[12];
  const float* bout = (const float*)d_in[13];
  float* out = (float*)d_out;

  // Workspace (float-slot offsets), disjoint:
  //  [0       , 2097152)  a1b bf16 [8192,512]
  //  [2097152 , 4194304)  khat fp32 [32,512,128]
  //  [4194304 , 6291456)  kT   fp32 [32,128,512]
  //  [6291456 , 6356992)  W1b bf16 131072
  //  [6356992 , 6422528)  W2b bf16 131072
  //  [6422528 , 6455296)  Wcb bf16 65536
  //  [6455296 , 6459392)  c [16,256]
  //  [6459392 , 6463488)  r [16,256]
  float* ws = (float*)d_ws;
  unsigned short* a1b = (unsigned short*)ws;
  float* khat = ws + 2097152;
  float* kT = ws + 4194304;
  unsigned short* W1b = (unsigned short*)(ws + 6291456);
  unsigned short* W2b = (unsigned short*)(ws + 6356992);
  unsigned short* Wcb = (unsigned short*)(ws + 6422528);
  float* c = ws + 6455296;
  float* r = ws + 6459392;

  // 1. weights -> bf16
  prep_kernel<<<1280, 256, 0, stream>>>(W1, W2, Wsem, Wepi, W1b, W2b, Wcb);
  // 2. a1 = relu(embed[seq] @ W1^T + b1) -> bf16
  gemm1_kernel<<<dim3(4, 64), 256, 0, stream>>>(seq, embed, W1b, b1, a1b);
  // 3. hn = LN(a1 @ W2^T + b2 + embed[seq]) [LDS] ; kproj + normalize -> khat/kT
  mlpk_kernel<<<256, 256, 0, stream>>>(a1b, W2b, b2, seq, embed, gamma, beta, Wcb, khat, kT);
  // 4. delta-rule scan -> c [16,256]  (packed-fp32 step)
  scan_kernel<<<256, 256, 0, stream>>>(khat, kT, c);
  // 5. r = c @ Wrp^T + brp
  rp_kernel<<<16, 256, 0, stream>>>(c, Wrp, brp, r);
  // 6. out = r @ Wout^T + bout
  out_kernel<<<500, 256, 0, stream>>>(r, Wout, bout, out);
}